// Round 1
// baseline (579.808 us; speedup 1.0000x reference)
//
#include <hip/hip_runtime.h>
#include <hip/hip_bf16.h>
#include <stdint.h>

#define CHUNKC 32
#define PRIORC 64
#define POSEC 512
#define PREDC 128
#define NB 2048
#define K1 (CHUNKC*POSEC)   // 16384

typedef __attribute__((ext_vector_type(8))) short bf16x8;
typedef __attribute__((ext_vector_type(4))) float f32x4;

__device__ __forceinline__ unsigned short f2b(float f) {
    union { float f; unsigned int u; } x; x.f = f;
    unsigned int r = x.u + 0x7fffu + ((x.u >> 16) & 1u);
    return (unsigned short)(r >> 16);
}

// ---------------- conversion kernels ----------------

// x = initial_feature[:, 32:64, :]  -> bf16  (2048 x 16384)
__global__ __launch_bounds__(256) void cvt_x_kernel(const float4* __restrict__ src,
                                                    ushort4* __restrict__ dst) {
    const int64_t n = (int64_t)NB * 4096;          // float4 count of x
    const int64_t stride = (int64_t)gridDim.x * blockDim.x;
    for (int64_t i = (int64_t)blockIdx.x * blockDim.x + threadIdx.x; i < n; i += stride) {
        int64_t b = i >> 12, r = i & 4095;
        float4 v = src[b * 8192 + 4096 + r];       // skip first 32 rows (4096 float4)
        dst[i] = make_ushort4(f2b(v.x), f2b(v.y), f2b(v.z), f2b(v.w));
    }
}

__global__ __launch_bounds__(256) void cvt_flat_kernel(const float4* __restrict__ src,
                                                       ushort4* __restrict__ dst, int64_t n4) {
    const int64_t stride = (int64_t)gridDim.x * blockDim.x;
    for (int64_t i = (int64_t)blockIdx.x * blockDim.x + threadIdx.x; i < n4; i += stride) {
        float4 v = src[i];
        dst[i] = make_ushort4(f2b(v.x), f2b(v.y), f2b(v.z), f2b(v.w));
    }
}

// ---------------- GEMM1: mem1 = x @ W1^T + b1 ----------------
// x: (2048,16384) bf16, W1: (512,16384) bf16, mem1: (2048,512) f32
// 64x64 tiles -> grid 32x8 = 256 WGs, 4 waves each.
__global__ __launch_bounds__(256) void gemm1_kernel(const ushort* __restrict__ xb,
                                                    const ushort* __restrict__ w1b,
                                                    const float* __restrict__ b1,
                                                    float* __restrict__ mem1) {
    __shared__ ushort As[64][72];   // pad 64->72: row stride 144B, no 128B-stride conflicts
    __shared__ ushort Bs[64][72];
    const int t = threadIdx.x;
    const int l = t & 63, wid = t >> 6;
    const int wr = wid >> 1, wc = wid & 1;         // 2x2 wave grid, 32x32 per wave
    const int mt = blockIdx.x >> 3, nt = blockIdx.x & 7;

    f32x4 acc[2][2] = {};

    const int sr = t >> 3, sc = t & 7;             // staging: 32 rows x 8 cols of 16B
    const ushort* aG = xb  + (int64_t)(mt * 64 + sr) * K1 + sc * 8;
    const ushort* bG = w1b + (int64_t)(nt * 64 + sr) * K1 + sc * 8;

    const int fr = l & 15, fk = (l >> 4) * 8;      // fragment row / k-offset

    for (int k0 = 0; k0 < K1; k0 += 64) {
        *(uint4*)&As[sr][sc * 8]      = *(const uint4*)(aG + k0);
        *(uint4*)&As[sr + 32][sc * 8] = *(const uint4*)(aG + (int64_t)32 * K1 + k0);
        *(uint4*)&Bs[sr][sc * 8]      = *(const uint4*)(bG + k0);
        *(uint4*)&Bs[sr + 32][sc * 8] = *(const uint4*)(bG + (int64_t)32 * K1 + k0);
        __syncthreads();
#pragma unroll
        for (int ks = 0; ks < 2; ++ks) {
            bf16x8 af[2], bfr[2];
#pragma unroll
            for (int mi = 0; mi < 2; ++mi)
                af[mi] = *(const bf16x8*)&As[wr * 32 + mi * 16 + fr][ks * 32 + fk];
#pragma unroll
            for (int ni = 0; ni < 2; ++ni)
                bfr[ni] = *(const bf16x8*)&Bs[wc * 32 + ni * 16 + fr][ks * 32 + fk];
#pragma unroll
            for (int mi = 0; mi < 2; ++mi)
#pragma unroll
                for (int ni = 0; ni < 2; ++ni)
                    acc[mi][ni] = __builtin_amdgcn_mfma_f32_16x16x32_bf16(af[mi], bfr[ni], acc[mi][ni], 0, 0, 0);
        }
        __syncthreads();
    }

    const int mbase = mt * 64 + wr * 32;
    const int nbase = nt * 64 + wc * 32;
#pragma unroll
    for (int mi = 0; mi < 2; ++mi)
#pragma unroll
        for (int ni = 0; ni < 2; ++ni) {
            int row0 = mbase + mi * 16 + (l >> 4) * 4;
            int col  = nbase + ni * 16 + (l & 15);
            float bias = b1[col];
#pragma unroll
            for (int r = 0; r < 4; ++r)
                mem1[(int64_t)(row0 + r) * POSEC + col] = acc[mi][ni][r] + bias;
        }
}

// ---------------- GEMM2: mem = mem1 @ W2^T + b2 ----------------
// mem1: (2048,512) f32, W2: (512,512) f32 -> cvt to bf16 during staging
__global__ __launch_bounds__(256) void gemm2_kernel(const float* __restrict__ A,
                                                    const float* __restrict__ W2,
                                                    const float* __restrict__ b2,
                                                    float* __restrict__ mem) {
    __shared__ ushort As[64][72];
    __shared__ ushort Bs[64][72];
    const int t = threadIdx.x;
    const int l = t & 63, wid = t >> 6;
    const int wr = wid >> 1, wc = wid & 1;
    const int mt = blockIdx.x >> 3, nt = blockIdx.x & 7;

    f32x4 acc[2][2] = {};
    const int sr = t >> 4, sc4 = t & 15;           // 16 rows x 16 float4 cols
    const int fr = l & 15, fk = (l >> 4) * 8;

    for (int k0 = 0; k0 < POSEC; k0 += 64) {
#pragma unroll
        for (int p = 0; p < 4; ++p) {
            int row = p * 16 + sr;
            float4 av = *(const float4*)&A [(int64_t)(mt * 64 + row) * POSEC + k0 + sc4 * 4];
            *(ushort4*)&As[row][sc4 * 4] = make_ushort4(f2b(av.x), f2b(av.y), f2b(av.z), f2b(av.w));
            float4 bv = *(const float4*)&W2[(int64_t)(nt * 64 + row) * POSEC + k0 + sc4 * 4];
            *(ushort4*)&Bs[row][sc4 * 4] = make_ushort4(f2b(bv.x), f2b(bv.y), f2b(bv.z), f2b(bv.w));
        }
        __syncthreads();
#pragma unroll
        for (int ks = 0; ks < 2; ++ks) {
            bf16x8 af[2], bfr[2];
#pragma unroll
            for (int mi = 0; mi < 2; ++mi)
                af[mi] = *(const bf16x8*)&As[wr * 32 + mi * 16 + fr][ks * 32 + fk];
#pragma unroll
            for (int ni = 0; ni < 2; ++ni)
                bfr[ni] = *(const bf16x8*)&Bs[wc * 32 + ni * 16 + fr][ks * 32 + fk];
#pragma unroll
            for (int mi = 0; mi < 2; ++mi)
#pragma unroll
                for (int ni = 0; ni < 2; ++ni)
                    acc[mi][ni] = __builtin_amdgcn_mfma_f32_16x16x32_bf16(af[mi], bfr[ni], acc[mi][ni], 0, 0, 0);
        }
        __syncthreads();
    }

    const int mbase = mt * 64 + wr * 32;
    const int nbase = nt * 64 + wc * 32;
#pragma unroll
    for (int mi = 0; mi < 2; ++mi)
#pragma unroll
        for (int ni = 0; ni < 2; ++ni) {
            int row0 = mbase + mi * 16 + (l >> 4) * 4;
            int col  = nbase + ni * 16 + (l & 15);
            float bias = b2[col];
#pragma unroll
            for (int r = 0; r < 4; ++r)
                mem[(int64_t)(row0 + r) * POSEC + col] = acc[mi][ni][r] + bias;
        }
}

// ---------------- score + sigmoid + blend + copy ----------------
// one block per batch element b
__global__ __launch_bounds__(256) void blend_kernel(const float* __restrict__ pred,
                                                    const float* __restrict__ mem,
                                                    float* __restrict__ out) {
    const int b = blockIdx.x;
    const int t = threadIdx.x;
    __shared__ float sm[POSEC];
    __shared__ float sg[CHUNKC];

    sm[t]       = mem[(int64_t)b * POSEC + t];
    sm[t + 256] = mem[(int64_t)b * POSEC + 256 + t];
    __syncthreads();

    const int l = t & 63, wid = t >> 6;
    const float4* sm4 = (const float4*)sm;
    const float4* p4 = (const float4*)pred + (int64_t)b * 16384;   // 128 rows * 128 float4
    float4* o4 = (float4*)out + (int64_t)b * 16384;

    // scores: wave `wid` handles c = wid*8 .. wid*8+7; each lane owns 8 dims
#pragma unroll
    for (int ci = 0; ci < 8; ++ci) {
        int c = wid * 8 + ci;
        float4 h0 = p4[c * 128 + l * 2];
        float4 h1 = p4[c * 128 + l * 2 + 1];
        float4 m0 = sm4[l * 2];
        float4 m1 = sm4[l * 2 + 1];
        float s = h0.x * m0.x + h0.y * m0.y + h0.z * m0.z + h0.w * m0.w
                + h1.x * m1.x + h1.y * m1.y + h1.z * m1.z + h1.w * m1.w;
#pragma unroll
        for (int o = 32; o; o >>= 1) s += __shfl_xor(s, o);
        if (l == 0) sg[c] = 1.0f / (1.0f + expf(-s));
    }
    __syncthreads();

    // blend rows 0..31  (4096 float4)
#pragma unroll
    for (int i = 0; i < 16; ++i) {
        int idx = i * 256 + t;
        int row = idx >> 7, c4 = idx & 127;
        float g = sg[row];
        float4 h = p4[idx];
        float4 m = sm4[c4];
        float4 r;
        r.x = g * h.x + (1.0f - g) * m.x;
        r.y = g * h.y + (1.0f - g) * m.y;
        r.z = g * h.z + (1.0f - g) * m.z;
        r.w = g * h.w + (1.0f - g) * m.w;
        o4[idx] = r;
    }
    // copy rows 32..127  (12288 float4)
#pragma unroll
    for (int i = 0; i < 48; ++i) {
        int idx = 4096 + i * 256 + t;
        o4[idx] = p4[idx];
    }
}

// ---------------- launch ----------------

extern "C" void kernel_launch(void* const* d_in, const int* in_sizes, int n_in,
                              void* d_out, int out_size, void* d_ws, size_t ws_size,
                              hipStream_t stream) {
    const float* init = (const float*)d_in[0];
    const float* pred = (const float*)d_in[1];
    const float* W1   = (const float*)d_in[2];
    const float* b1   = (const float*)d_in[3];
    const float* W2   = (const float*)d_in[4];
    const float* b2   = (const float*)d_in[5];
    float* out = (float*)d_out;

    char* ws = (char*)d_ws;
    ushort* xb   = (ushort*)ws;                        // 2048*16384*2 = 67108864 B
    ushort* w1b  = (ushort*)(ws + 67108864);           // 512*16384*2  = 16777216 B
    float*  mem1 = (float*)(ws + 83886080);            // 2048*512*4   = 4194304 B
    float*  mem  = (float*)(ws + 88080384);            // 2048*512*4   = 4194304 B

    cvt_x_kernel<<<2048, 256, 0, stream>>>((const float4*)init, (ushort4*)xb);
    cvt_flat_kernel<<<1024, 256, 0, stream>>>((const float4*)W1, (ushort4*)w1b,
                                              (int64_t)POSEC * K1 / 4);
    gemm1_kernel<<<256, 256, 0, stream>>>(xb, w1b, b1, mem1);
    gemm2_kernel<<<256, 256, 0, stream>>>(mem1, W2, b2, mem);
    blend_kernel<<<NB, 256, 0, stream>>>(pred, mem, out);
}

// Round 2
// 335.826 us; speedup vs baseline: 1.7265x; 1.7265x over previous
//
#include <hip/hip_runtime.h>
#include <hip/hip_bf16.h>
#include <stdint.h>

#define CHUNKC 32
#define PRIORC 64
#define POSEC 512
#define PREDC 128
#define NB 2048
#define K1 (CHUNKC*POSEC)   // 16384
#define KS 8                // split-K factor for gemm1
#define KCH (K1/KS)         // 2048

typedef __attribute__((ext_vector_type(8))) short bf16x8;
typedef __attribute__((ext_vector_type(4))) float f32x4;

__device__ __forceinline__ unsigned short f2b(float f) {
    union { float f; unsigned int u; } x; x.f = f;
    unsigned int r = x.u + 0x7fffu + ((x.u >> 16) & 1u);
    return (unsigned short)(r >> 16);
}

__device__ __forceinline__ void gload_lds16(const void* g, void* l) {
    __builtin_amdgcn_global_load_lds(
        (const __attribute__((address_space(1))) unsigned int*)g,
        (__attribute__((address_space(3))) unsigned int*)l, 16, 0, 0);
}

// ---------------- conversion kernels ----------------

// x = initial_feature[:, 32:64, :] -> bf16 (2048 x 16384)
__global__ __launch_bounds__(256) void cvt_x_kernel(const float4* __restrict__ src,
                                                    ushort4* __restrict__ dst) {
    const int64_t n = (int64_t)NB * 4096;
    const int64_t stride = (int64_t)gridDim.x * blockDim.x;
    for (int64_t i = (int64_t)blockIdx.x * blockDim.x + threadIdx.x; i < n; i += stride) {
        int64_t b = i >> 12, r = i & 4095;
        float4 v = src[b * 8192 + 4096 + r];
        dst[i] = make_ushort4(f2b(v.x), f2b(v.y), f2b(v.z), f2b(v.w));
    }
}

__global__ __launch_bounds__(256) void cvt_flat_kernel(const float4* __restrict__ src,
                                                       ushort4* __restrict__ dst, int64_t n4) {
    const int64_t stride = (int64_t)gridDim.x * blockDim.x;
    for (int64_t i = (int64_t)blockIdx.x * blockDim.x + threadIdx.x; i < n4; i += stride) {
        float4 v = src[i];
        dst[i] = make_ushort4(f2b(v.x), f2b(v.y), f2b(v.z), f2b(v.w));
    }
}

// ---------------- GEMM1: partials of x @ W1^T ----------------
// x: (2048,16384) bf16, W1: (512,16384) bf16.
// m97 structure: 128x128 tile, BK=64, 4 waves, 4x4 frags/wave, global_load_lds.
// split-K=8: grid = 16 mt * 4 nt * 8 ks = 512 WGs (2/CU).
__global__ __launch_bounds__(256) void gemm1_kernel(const ushort* __restrict__ xb,
                                                    const ushort* __restrict__ w1b,
                                                    float* __restrict__ part) {
    __shared__ ushort As[128][64];   // 16 KB, linear (required by global_load_lds)
    __shared__ ushort Bs[128][64];
    const int t = threadIdx.x;
    const int l = t & 63, wid = t >> 6;
    const int wr = wid >> 1, wc = wid & 1;          // 2x2 waves, 64x64 out each
    const int bid = blockIdx.x;
    const int mt = bid & 15, nt = (bid >> 4) & 3, ks = bid >> 6;

    f32x4 acc[4][4] = {};

    const ushort* aG = xb  + (int64_t)(mt * 128) * K1 + ks * KCH;
    const ushort* bG = w1b + (int64_t)(nt * 128) * K1 + ks * KCH;
    const int srow = t >> 3, scol = (t & 7) * 8;    // thread's 16B within a 32-row chunk

    const int fr = l & 15, fq = l >> 4;             // fragment row / k-quad

    for (int k0 = 0; k0 < KCH; k0 += 64) {
#pragma unroll
        for (int i = 0; i < 4; ++i) {               // 4 chunks of 32 rows, A and B
            gload_lds16(aG + (int64_t)(i * 32 + srow) * K1 + k0 + scol,
                        (char*)&As[0][0] + i * 4096 + wid * 1024);
            gload_lds16(bG + (int64_t)(i * 32 + srow) * K1 + k0 + scol,
                        (char*)&Bs[0][0] + i * 4096 + wid * 1024);
        }
        __syncthreads();
#pragma unroll
        for (int k2 = 0; k2 < 2; ++k2) {
            bf16x8 a[4], b[4];
#pragma unroll
            for (int m = 0; m < 4; ++m)
                a[m] = *(const bf16x8*)&As[wr * 64 + m * 16 + fr][k2 * 32 + fq * 8];
#pragma unroll
            for (int n = 0; n < 4; ++n)
                b[n] = *(const bf16x8*)&Bs[wc * 64 + n * 16 + fr][k2 * 32 + fq * 8];
#pragma unroll
            for (int m = 0; m < 4; ++m)
#pragma unroll
                for (int n = 0; n < 4; ++n)
                    acc[m][n] = __builtin_amdgcn_mfma_f32_16x16x32_bf16(a[m], b[n], acc[m][n], 0, 0, 0);
        }
        __syncthreads();
    }

    float* P = part + (int64_t)ks * NB * POSEC;
    const int mbase = mt * 128 + wr * 64, nbase = nt * 128 + wc * 64;
#pragma unroll
    for (int m = 0; m < 4; ++m)
#pragma unroll
        for (int n = 0; n < 4; ++n) {
            int row0 = mbase + m * 16 + fq * 4;
            int col  = nbase + n * 16 + fr;
#pragma unroll
            for (int r = 0; r < 4; ++r)
                P[(int64_t)(row0 + r) * POSEC + col] = acc[m][n][r];
        }
}

// ---------------- reduce: A2 = bf16(sum_ks part + b1) ----------------
__global__ __launch_bounds__(256) void reduce_kernel(const float4* __restrict__ part,
                                                     const float* __restrict__ b1,
                                                     ushort4* __restrict__ A2) {
    const int i4 = blockIdx.x * 256 + threadIdx.x;      // 262144 float4 total
    float4 s = part[i4];
#pragma unroll
    for (int k = 1; k < KS; ++k) {
        float4 p = part[(int64_t)k * 262144 + i4];
        s.x += p.x; s.y += p.y; s.z += p.z; s.w += p.w;
    }
    const int col = (i4 * 4) & 511;
    float4 bv = *(const float4*)&b1[col];
    A2[i4] = make_ushort4(f2b(s.x + bv.x), f2b(s.y + bv.y), f2b(s.z + bv.z), f2b(s.w + bv.w));
}

// ---------------- GEMM2: mem = A2 @ W2b^T + b2 ----------------
// A2: (2048,512) bf16, W2b: (512,512) bf16, mem: (2048,512) f32.
// 64x64 tiles, grid 32x8 = 256 WGs, global_load_lds staging, K=512.
__global__ __launch_bounds__(256) void gemm2_kernel(const ushort* __restrict__ A2,
                                                    const ushort* __restrict__ w2b,
                                                    const float* __restrict__ b2,
                                                    float* __restrict__ mem) {
    __shared__ ushort As[64][64];   // 8 KB
    __shared__ ushort Bs[64][64];
    const int t = threadIdx.x;
    const int l = t & 63, wid = t >> 6;
    const int wr = wid >> 1, wc = wid & 1;          // 2x2 waves, 32x32 out each
    const int mt = blockIdx.x >> 3, nt = blockIdx.x & 7;

    f32x4 acc[2][2] = {};
    const ushort* aG = A2  + (int64_t)(mt * 64) * POSEC;
    const ushort* bG = w2b + (int64_t)(nt * 64) * POSEC;
    const int srow = t >> 3, scol = (t & 7) * 8;
    const int fr = l & 15, fq = l >> 4;

    for (int k0 = 0; k0 < POSEC; k0 += 64) {
#pragma unroll
        for (int i = 0; i < 2; ++i) {               // 2 chunks of 32 rows
            gload_lds16(aG + (int64_t)(i * 32 + srow) * POSEC + k0 + scol,
                        (char*)&As[0][0] + i * 4096 + wid * 1024);
            gload_lds16(bG + (int64_t)(i * 32 + srow) * POSEC + k0 + scol,
                        (char*)&Bs[0][0] + i * 4096 + wid * 1024);
        }
        __syncthreads();
#pragma unroll
        for (int k2 = 0; k2 < 2; ++k2) {
            bf16x8 a[2], b[2];
#pragma unroll
            for (int m = 0; m < 2; ++m)
                a[m] = *(const bf16x8*)&As[wr * 32 + m * 16 + fr][k2 * 32 + fq * 8];
#pragma unroll
            for (int n = 0; n < 2; ++n)
                b[n] = *(const bf16x8*)&Bs[wc * 32 + n * 16 + fr][k2 * 32 + fq * 8];
#pragma unroll
            for (int m = 0; m < 2; ++m)
#pragma unroll
                for (int n = 0; n < 2; ++n)
                    acc[m][n] = __builtin_amdgcn_mfma_f32_16x16x32_bf16(a[m], b[n], acc[m][n], 0, 0, 0);
        }
        __syncthreads();
    }

    const int mbase = mt * 64 + wr * 32, nbase = nt * 64 + wc * 32;
#pragma unroll
    for (int m = 0; m < 2; ++m)
#pragma unroll
        for (int n = 0; n < 2; ++n) {
            int row0 = mbase + m * 16 + fq * 4;
            int col  = nbase + n * 16 + fr;
            float bias = b2[col];
#pragma unroll
            for (int r = 0; r < 4; ++r)
                mem[(int64_t)(row0 + r) * POSEC + col] = acc[m][n][r] + bias;
        }
}

// ---------------- score + sigmoid + blend + copy ----------------
__global__ __launch_bounds__(256) void blend_kernel(const float* __restrict__ pred,
                                                    const float* __restrict__ mem,
                                                    float* __restrict__ out) {
    const int b = blockIdx.x;
    const int t = threadIdx.x;
    __shared__ float sm[POSEC];
    __shared__ float sg[CHUNKC];

    sm[t]       = mem[(int64_t)b * POSEC + t];
    sm[t + 256] = mem[(int64_t)b * POSEC + 256 + t];
    __syncthreads();

    const int l = t & 63, wid = t >> 6;
    const float4* sm4 = (const float4*)sm;
    const float4* p4 = (const float4*)pred + (int64_t)b * 16384;
    float4* o4 = (float4*)out + (int64_t)b * 16384;

#pragma unroll
    for (int ci = 0; ci < 8; ++ci) {
        int c = wid * 8 + ci;
        float4 h0 = p4[c * 128 + l * 2];
        float4 h1 = p4[c * 128 + l * 2 + 1];
        float4 m0 = sm4[l * 2];
        float4 m1 = sm4[l * 2 + 1];
        float s = h0.x * m0.x + h0.y * m0.y + h0.z * m0.z + h0.w * m0.w
                + h1.x * m1.x + h1.y * m1.y + h1.z * m1.z + h1.w * m1.w;
#pragma unroll
        for (int o = 32; o; o >>= 1) s += __shfl_xor(s, o);
        if (l == 0) sg[c] = 1.0f / (1.0f + expf(-s));
    }
    __syncthreads();

#pragma unroll
    for (int i = 0; i < 16; ++i) {
        int idx = i * 256 + t;
        int row = idx >> 7, c4 = idx & 127;
        float g = sg[row];
        float4 h = p4[idx];
        float4 m = sm4[c4];
        float4 r;
        r.x = g * h.x + (1.0f - g) * m.x;
        r.y = g * h.y + (1.0f - g) * m.y;
        r.z = g * h.z + (1.0f - g) * m.z;
        r.w = g * h.w + (1.0f - g) * m.w;
        o4[idx] = r;
    }
#pragma unroll
    for (int i = 0; i < 48; ++i) {
        int idx = 4096 + i * 256 + t;
        o4[idx] = p4[idx];
    }
}

// ---------------- launch ----------------

extern "C" void kernel_launch(void* const* d_in, const int* in_sizes, int n_in,
                              void* d_out, int out_size, void* d_ws, size_t ws_size,
                              hipStream_t stream) {
    const float* init = (const float*)d_in[0];
    const float* pred = (const float*)d_in[1];
    const float* W1   = (const float*)d_in[2];
    const float* b1   = (const float*)d_in[3];
    const float* W2   = (const float*)d_in[4];
    const float* b2   = (const float*)d_in[5];
    float* out = (float*)d_out;

    char* ws = (char*)d_ws;
    ushort* xb   = (ushort*)(ws);                       // 67108864 B
    ushort* w1b  = (ushort*)(ws + 67108864);            // 16777216 B
    ushort* w2b  = (ushort*)(ws + 83886080);            //   524288 B
    float*  part = (float*) (ws + 84410368);            // 33554432 B (8 x 2048 x 512 f32)
    ushort* A2   = (ushort*)(ws + 117964800);           //  2097152 B
    float*  mem  = (float*) (ws + 120061952);           //  4194304 B

    cvt_x_kernel<<<2048, 256, 0, stream>>>((const float4*)init, (ushort4*)xb);
    cvt_flat_kernel<<<1024, 256, 0, stream>>>((const float4*)W1, (ushort4*)w1b,
                                              (int64_t)POSEC * K1 / 4);
    cvt_flat_kernel<<<256, 256, 0, stream>>>((const float4*)W2, (ushort4*)w2b,
                                             (int64_t)POSEC * POSEC / 4);
    gemm1_kernel<<<512, 256, 0, stream>>>(xb, w1b, part);
    reduce_kernel<<<1024, 256, 0, stream>>>((const float4*)part, b1, (ushort4*)A2);
    gemm2_kernel<<<256, 256, 0, stream>>>(A2, w2b, b2, mem);
    blend_kernel<<<NB, 256, 0, stream>>>(pred, mem, out);
}